// Round 7
// baseline (248.753 us; speedup 1.0000x reference)
//
#include <hip/hip_runtime.h>

#define INDIM 256
#define HID 128
#define OUTD 64
#define BINSHIFT 8
#define MAXBIN 256   // supports M <= 65536
#define CW 32        // feature chunk width (64 B fp16 rows -> slice fits 4 MB per-XCD L2)

typedef _Float16 f16x8 __attribute__((ext_vector_type(8)));
typedef float    f32x4 __attribute__((ext_vector_type(4)));

// =============== setup: weight transpose/convert + zero bin counts ===============
__global__ __launch_bounds__(256) void k_setup(const float* __restrict__ W1, const float* __restrict__ W2,
                                               _Float16* __restrict__ W1t, _Float16* __restrict__ W2t,
                                               int* __restrict__ bin_counts) {
    constexpr int NW1 = HID * INDIM;   // 32768
    constexpr int NW2 = OUTD * HID;    // 8192
    int id = blockIdx.x * 256 + threadIdx.x;
    if (id < NW1) {
        int n = id / INDIM, k = id % INDIM;
        W1t[id] = (_Float16)W1[k * HID + n];
    } else if (id < NW1 + NW2) {
        int j = id - NW1;
        int n = j / HID, k = j % HID;
        W2t[j] = (_Float16)W2[k * OUTD + n];
    } else {
        int i = id - NW1 - NW2;
        if (i < MAXBIN) bin_counts[i] = 0;
    }
}

// =============== binned CSR build ===============
__global__ __launch_bounds__(256) void k_hist(const int* __restrict__ dst, int* __restrict__ bin_counts, int E) {
    __shared__ int h[MAXBIN];
    int tid = threadIdx.x;
    h[tid] = 0;
    __syncthreads();
    int base = blockIdx.x * 2048;
#pragma unroll
    for (int i = 0; i < 8; i++) {
        int e = base + i * 256 + tid;
        if (e < E) atomicAdd(&h[dst[e] >> BINSHIFT], 1);
    }
    __syncthreads();
    int v = h[tid];
    if (v) atomicAdd(&bin_counts[tid], v);
}

__global__ __launch_bounds__(256) void k_bscan(const int* __restrict__ bin_counts,
                                               int* __restrict__ bin_start, int* __restrict__ bin_cursor,
                                               int* __restrict__ row_start, int NBIN, int M, int E) {
    __shared__ int s[256];
    int tid = threadIdx.x;
    int v = (tid < NBIN) ? bin_counts[tid] : 0;
    s[tid] = v;
    __syncthreads();
#pragma unroll
    for (int off = 1; off < 256; off <<= 1) {
        int t = (tid >= off) ? s[tid - off] : 0;
        __syncthreads();
        s[tid] += t;
        __syncthreads();
    }
    if (tid < NBIN) {
        int excl = s[tid] - v;
        bin_start[tid] = excl;
        bin_cursor[tid] = excl;
    }
    if (tid == 0) {
        bin_start[NBIN] = E;
        row_start[M] = E;
    }
}

__global__ __launch_bounds__(256) void k_binfill(const int* __restrict__ src, const int* __restrict__ dst,
                                                 int* __restrict__ bin_cursor, int2* __restrict__ binned, int E) {
    __shared__ int h[MAXBIN];
    __shared__ int rb[MAXBIN];
    int tid = threadIdx.x;
    h[tid] = 0;
    __syncthreads();
    int base = blockIdx.x * 2048;
    int es[8], ed[8], rk[8];
#pragma unroll
    for (int i = 0; i < 8; i++) {
        int e = base + i * 256 + tid;
        if (e < E) {
            es[i] = src[e];
            ed[i] = dst[e];
            rk[i] = atomicAdd(&h[ed[i] >> BINSHIFT], 1);
        } else {
            ed[i] = -1;
        }
    }
    __syncthreads();
    int c = h[tid];
    if (c) rb[tid] = atomicAdd(&bin_cursor[tid], c);
    __syncthreads();
#pragma unroll
    for (int i = 0; i < 8; i++) {
        if (ed[i] >= 0) {
            binned[rb[ed[i] >> BINSHIFT] + rk[i]] = make_int2(es[i], ed[i]);
        }
    }
}

__global__ __launch_bounds__(256) void k_csr(const int2* __restrict__ binned, const int* __restrict__ bin_start,
                                             int* __restrict__ row_start, float* __restrict__ dinv,
                                             int* __restrict__ edge_src, int M) {
    __shared__ int cnt[256];
    __shared__ int s[256];
    __shared__ int cur[256];
    int b = blockIdx.x, tid = threadIdx.x;
    int beg = bin_start[b], end = bin_start[b + 1];
    cnt[tid] = 0;
    __syncthreads();
    for (int i = beg + tid; i < end; i += 256) {
        atomicAdd(&cnt[binned[i].y & 255], 1);
    }
    __syncthreads();
    int c = cnt[tid];
    s[tid] = c;
    __syncthreads();
#pragma unroll
    for (int off = 1; off < 256; off <<= 1) {
        int t = (tid >= off) ? s[tid - off] : 0;
        __syncthreads();
        s[tid] += t;
        __syncthreads();
    }
    int start = beg + s[tid] - c;
    int node = (b << BINSHIFT) + tid;
    if (node < M) {
        row_start[node] = start;
        dinv[node] = rsqrtf(1.0f + (float)c);
    }
    cur[tid] = start;
    __syncthreads();
    for (int i = beg + tid; i < end; i += 256) {
        int2 e = binned[i];
        int pos = atomicAdd(&cur[e.y & 255], 1);
        edge_src[pos] = e.x;
    }
}

// =============== MFMA fp16 GEMM, pre-scaled fp16 output in CHUNK layout ===============
// X: fp32 row-major [M][K]  OR  fp16 chunk tables [K/CW][M][CW].
// Output XW16: chunk tables [BN/CW][M][CW], values (X@W)[row][col] * dinv[row].
template <int BN, int K, typename AT>
__global__ __launch_bounds__(256) void k_gemm_mfma(
    const AT* __restrict__ X, const _Float16* __restrict__ Wt,
    const float* __restrict__ dinv, _Float16* __restrict__ XW16, int M)
{
    constexpr int BM = 64;
    constexpr int BK = 32;
    constexpr int NT = BN / 16;
    constexpr int LDK = BK + 8;   // 40 halfs = 80 B stride, 16B-aligned

    __shared__ __align__(16) _Float16 As[BM][LDK];
    __shared__ __align__(16) _Float16 Bs[BN][LDK];

    const int tid  = threadIdx.x;
    const int wave = tid >> 6;
    const int lane = tid & 63;
    const int m    = lane & 15;
    const int q    = lane >> 4;
    const int rb   = blockIdx.x * BM;

    f32x4 acc[NT];
#pragma unroll
    for (int t = 0; t < NT; t++) acc[t] = (f32x4){0.f, 0.f, 0.f, 0.f};

    for (int kt = 0; kt < K; kt += BK) {
        if (kt) __syncthreads();
        if constexpr (sizeof(AT) == 4) {
            // fp32 row-major A
#pragma unroll
            for (int i = 0; i < BM * 8 / 256; i++) {
                int ch  = tid + i * 256;
                int row = ch >> 3;
                int c4  = ch & 7;
                int gr  = rb + row;
                float4 v = make_float4(0.f, 0.f, 0.f, 0.f);
                if (gr < M) v = *(const float4*)((const float*)X + (long)gr * K + kt + c4 * 4);
                _Float16* p = &As[row][c4 * 4];
                p[0] = (_Float16)v.x; p[1] = (_Float16)v.y;
                p[2] = (_Float16)v.z; p[3] = (_Float16)v.w;
            }
        } else {
            // fp16 chunk-table A: k-tile kt is exactly chunk kt/CW (BK == CW)
            int row = tid >> 2;
            int c8  = tid & 3;
            int gr  = rb + row;
            uint4 v = make_uint4(0u, 0u, 0u, 0u);
            if (gr < M)
                v = *(const uint4*)((const _Float16*)X + ((long)(kt / CW) * M + gr) * CW + c8 * 8);
            *(uint4*)(&As[row][c8 * 8]) = v;
        }
#pragma unroll
        for (int i = 0; i < BN * 8 / 256; i++) {
            int ch = tid + i * 256;
            int n  = ch >> 3;
            int c4 = ch & 7;
            *(ushort4*)(&Bs[n][c4 * 4]) =
                *(const ushort4*)(Wt + (long)n * K + kt + c4 * 4);
        }
        __syncthreads();

        f16x8 af = *(const f16x8*)(&As[wave * 16 + m][q * 8]);
#pragma unroll
        for (int t = 0; t < NT; t++) {
            f16x8 bf = *(const f16x8*)(&Bs[t * 16 + m][q * 8]);
            acc[t] = __builtin_amdgcn_mfma_f32_16x16x32_f16(af, bf, acc[t], 0, 0, 0);
        }
    }

    // epilogue: C/D layout col=lane&15, row=quad*4+reg; scale by dinv, chunked store
    int row0 = rb + wave * 16 + q * 4;
#pragma unroll
    for (int r = 0; r < 4; r++) {
        int row = row0 + r;
        if (row < M) {
            float di = dinv[row];
#pragma unroll
            for (int t = 0; t < NT; t++) {
                int col = t * 16 + m;
                XW16[((long)(col / CW) * M + row) * CW + (col & (CW - 1))] =
                    (_Float16)(acc[t][r] * di);
            }
        }
    }
}

// =============== CSR gather-aggregation, one 32-column chunk ===============
// featc: this chunk's [M][32] pre-scaled fp16 table (3.2 MB -> fits per-XCD L2).
// outc (fp16): chunk table [M][32]; outc (fp32): row-major, pre-offset to chunk cols, stride OS.
// out[n] = act(biasc + dinv[n] * (featc[n] + sum_{e in(n)} featc[src_e]))
template <bool TANH, typename OutT>
__global__ __launch_bounds__(256) void k_agg_chunk(const int* __restrict__ row_start,
                                                   const int* __restrict__ edge_src,
                                                   const _Float16* __restrict__ featc,
                                                   const float* __restrict__ biasc,
                                                   const float* __restrict__ dinv,
                                                   OutT* __restrict__ outc, int OS, int M) {
    constexpr int LPN = CW / 8;   // 4 lanes per node, 16 B each
    int n = blockIdx.x * (256 / LPN) + threadIdx.x / LPN;
    int c = threadIdx.x % LPN;
    if (n >= M) return;
    int beg = row_start[n], end = row_start[n + 1];

    f16x8 self = *(const f16x8*)(featc + (long)n * CW + c * 8);
    float acc[8];
#pragma unroll
    for (int k = 0; k < 8; k++) acc[k] = (float)self[k];

    int j = beg;
    for (; j + 3 < end; j += 4) {
        int s0 = edge_src[j], s1 = edge_src[j + 1];
        int s2 = edge_src[j + 2], s3 = edge_src[j + 3];
        f16x8 v0 = *(const f16x8*)(featc + (long)s0 * CW + c * 8);
        f16x8 v1 = *(const f16x8*)(featc + (long)s1 * CW + c * 8);
        f16x8 v2 = *(const f16x8*)(featc + (long)s2 * CW + c * 8);
        f16x8 v3 = *(const f16x8*)(featc + (long)s3 * CW + c * 8);
#pragma unroll
        for (int k = 0; k < 8; k++)
            acc[k] += ((float)v0[k] + (float)v1[k]) + ((float)v2[k] + (float)v3[k]);
    }
    for (; j < end; j++) {
        int s = edge_src[j];
        f16x8 v = *(const f16x8*)(featc + (long)s * CW + c * 8);
#pragma unroll
        for (int k = 0; k < 8; k++) acc[k] += (float)v[k];
    }

    float di = dinv[n];
#pragma unroll
    for (int k = 0; k < 8; k++) acc[k] = biasc[c * 8 + k] + di * acc[k];
    if (TANH) {
#pragma unroll
        for (int k = 0; k < 8; k++) acc[k] = tanhf(acc[k]);
    }
    if constexpr (sizeof(OutT) == 2) {
        f16x8 o;
#pragma unroll
        for (int k = 0; k < 8; k++) o[k] = (_Float16)acc[k];
        *(f16x8*)((_Float16*)outc + (long)n * OS + c * 8) = o;
    } else {
        float* p = (float*)outc + (long)n * OS + c * 8;
        *(float4*)(p)     = make_float4(acc[0], acc[1], acc[2], acc[3]);
        *(float4*)(p + 4) = make_float4(acc[4], acc[5], acc[6], acc[7]);
    }
}

extern "C" void kernel_launch(void* const* d_in, const int* in_sizes, int n_in,
                              void* d_out, int out_size, void* d_ws, size_t ws_size,
                              hipStream_t stream) {
    const float* x  = (const float*)d_in[0];
    const int*   ei = (const int*)d_in[1];
    const float* W1 = (const float*)d_in[2];
    const float* b1 = (const float*)d_in[3];
    const float* W2 = (const float*)d_in[4];
    const float* b2 = (const float*)d_in[5];
    float* out = (float*)d_out;

    const int M = in_sizes[0] / INDIM;   // 50000
    const int E = in_sizes[1] / 2;       // 800000
    const int* srcp = ei;
    const int* dstp = ei + E;

    const int Mp   = (M + 63) & ~63;
    const int NBIN = (M + 255) >> BINSHIFT;  // 196

    // workspace layout (int2 array 8B-aligned)
    float*     dinv       = (float*)d_ws;
    int*       row_start  = (int*)(dinv + Mp);            // [M+1] <= Mp
    int*       bin_start  = row_start + Mp;               // [NBIN+1], padded 258
    int*       bin_cursor = bin_start + 258;
    int*       bin_counts = bin_cursor + MAXBIN;
    _Float16*  W1t        = (_Float16*)(bin_counts + MAXBIN);  // [HID][INDIM]
    _Float16*  W2t        = W1t + HID * INDIM;                 // [OUTD][HID]
    int2*      binned     = (int2*)(W2t + OUTD * HID);         // [E]
    int*       edge_src   = (int*)(binned + E);                // [E]
    _Float16*  xw16       = (_Float16*)(edge_src + E);         // [HID/CW][M][CW]
    _Float16*  h16        = xw16 + (long)M * HID;              // [HID/CW][M][CW]
    _Float16*  hw16       = xw16;                              // alias: xw dead after agg1

    const int NWE = (E + 2047) / 2048;

    // ---- setup + binned CSR build ----
    {
        int total = HID * INDIM + OUTD * HID + MAXBIN;
        k_setup<<<(total + 255) / 256, 256, 0, stream>>>(W1, W2, W1t, W2t, bin_counts);
    }
    k_hist<<<NWE, 256, 0, stream>>>(dstp, bin_counts, E);
    k_bscan<<<1, 256, 0, stream>>>(bin_counts, bin_start, bin_cursor, row_start, NBIN, M, E);
    k_binfill<<<NWE, 256, 0, stream>>>(srcp, dstp, bin_cursor, binned, E);
    k_csr<<<NBIN, 256, 0, stream>>>(binned, bin_start, row_start, dinv, edge_src, M);

    const int GA = (M + 63) / 64;   // agg grid (64 nodes per block)

    // ---- layer 1 ----
    k_gemm_mfma<HID, INDIM, float><<<(M + 63) / 64, 256, 0, stream>>>(x, W1t, dinv, xw16, M);
#pragma unroll
    for (int ch = 0; ch < HID / CW; ch++) {
        k_agg_chunk<true, _Float16><<<GA, 256, 0, stream>>>(
            row_start, edge_src, xw16 + (long)ch * M * CW, b1 + ch * CW, dinv,
            h16 + (long)ch * M * CW, CW, M);
    }

    // ---- layer 2 ----
    k_gemm_mfma<OUTD, HID, _Float16><<<(M + 63) / 64, 256, 0, stream>>>(h16, W2t, dinv, hw16, M);
#pragma unroll
    for (int ch = 0; ch < OUTD / CW; ch++) {
        k_agg_chunk<false, float><<<GA, 256, 0, stream>>>(
            row_start, edge_src, hw16 + (long)ch * M * CW, b2 + ch * CW, dinv,
            out + ch * CW, OUTD, M);
    }
}

// Round 8
// 229.699 us; speedup vs baseline: 1.0830x; 1.0830x over previous
//
#include <hip/hip_runtime.h>

#define INDIM 256
#define HID 128
#define OUTD 64
#define BINSHIFT 8
#define MAXBIN 256   // supports M <= 65536

typedef _Float16 f16x8 __attribute__((ext_vector_type(8)));
typedef float    f32x4 __attribute__((ext_vector_type(4)));

// =============== pass 1: per-wg LDS histogram of dst>>8  (+ fused weight prep) ===============
__global__ __launch_bounds__(256) void k_hist_setup(const int* __restrict__ dst, int* __restrict__ bin_counts,
                                                    int E,
                                                    const float* __restrict__ W1, const float* __restrict__ W2,
                                                    _Float16* __restrict__ W1t, _Float16* __restrict__ W2t) {
    __shared__ int h[MAXBIN];
    int tid = threadIdx.x;
    h[tid] = 0;
    __syncthreads();
    int base = blockIdx.x * 4096;
#pragma unroll
    for (int i = 0; i < 16; i++) {
        int e = base + i * 256 + tid;
        if (e < E) atomicAdd(&h[dst[e] >> BINSHIFT], 1);
    }
    __syncthreads();
    int v = h[tid];
    if (v) atomicAdd(&bin_counts[tid], v);

    // fused weight transpose/convert (independent of histogram)
    constexpr int NW1 = HID * INDIM;   // 32768
    constexpr int NW2 = OUTD * HID;    // 8192
    int id = blockIdx.x * 256 + tid;
    if (id < NW1) {
        int n = id / INDIM, k = id % INDIM;
        W1t[id] = (_Float16)W1[k * HID + n];
    } else if (id < NW1 + NW2) {
        int j = id - NW1;
        int n = j / HID, k = j % HID;
        W2t[j] = (_Float16)W2[k * OUTD + n];
    }
}

// =============== pass 2: exclusive scan of bin counts (1 wg) ===============
__global__ __launch_bounds__(256) void k_bscan(const int* __restrict__ bin_counts,
                                               int* __restrict__ bin_start, int* __restrict__ bin_cursor,
                                               int* __restrict__ row_start, int NBIN, int M, int E) {
    __shared__ int s[256];
    int tid = threadIdx.x;
    int v = (tid < NBIN) ? bin_counts[tid] : 0;
    s[tid] = v;
    __syncthreads();
#pragma unroll
    for (int off = 1; off < 256; off <<= 1) {
        int t = (tid >= off) ? s[tid - off] : 0;
        __syncthreads();
        s[tid] += t;
        __syncthreads();
    }
    if (tid < NBIN) {
        int excl = s[tid] - v;
        bin_start[tid] = excl;
        bin_cursor[tid] = excl;
    }
    if (tid == 0) {
        bin_start[NBIN] = E;
        row_start[M] = E;
    }
}

// =============== pass 3: scatter packed (src<<8 | dst&255) into bin runs ===============
__global__ __launch_bounds__(256) void k_binfill(const int* __restrict__ src, const int* __restrict__ dst,
                                                 int* __restrict__ bin_cursor, int* __restrict__ binned, int E) {
    __shared__ int h[MAXBIN];
    __shared__ int rb[MAXBIN];
    int tid = threadIdx.x;
    h[tid] = 0;
    __syncthreads();
    int base = blockIdx.x * 2048;
    int ep[8], eb[8], rk[8];
#pragma unroll
    for (int i = 0; i < 8; i++) {
        int e = base + i * 256 + tid;
        if (e < E) {
            int s = src[e], d = dst[e];
            ep[i] = (s << 8) | (d & 255);
            eb[i] = d >> BINSHIFT;
            rk[i] = atomicAdd(&h[eb[i]], 1);
        } else {
            eb[i] = -1;
        }
    }
    __syncthreads();
    int c = h[tid];
    if (c) rb[tid] = atomicAdd(&bin_cursor[tid], c);
    __syncthreads();
#pragma unroll
    for (int i = 0; i < 8; i++) {
        if (eb[i] >= 0) binned[rb[eb[i]] + rk[i]] = ep[i];
    }
}

// =============== pass 4: per-bin CSR finalize (row_start, dinv, edge_src) ===============
__global__ __launch_bounds__(256) void k_csr(const int* __restrict__ binned, const int* __restrict__ bin_start,
                                             int* __restrict__ row_start, float* __restrict__ dinv,
                                             int* __restrict__ edge_src, int M) {
    __shared__ int cnt[256];
    __shared__ int s[256];
    __shared__ int cur[256];
    int b = blockIdx.x, tid = threadIdx.x;
    int beg = bin_start[b], end = bin_start[b + 1];
    cnt[tid] = 0;
    __syncthreads();
    for (int i = beg + tid; i < end; i += 256) {
        atomicAdd(&cnt[binned[i] & 255], 1);
    }
    __syncthreads();
    int c = cnt[tid];
    s[tid] = c;
    __syncthreads();
#pragma unroll
    for (int off = 1; off < 256; off <<= 1) {
        int t = (tid >= off) ? s[tid - off] : 0;
        __syncthreads();
        s[tid] += t;
        __syncthreads();
    }
    int start = beg + s[tid] - c;
    int node = (b << BINSHIFT) + tid;
    if (node < M) {
        row_start[node] = start;
        dinv[node] = rsqrtf(1.0f + (float)c);
    }
    cur[tid] = start;
    __syncthreads();
    for (int i = beg + tid; i < end; i += 256) {
        int p = binned[i];
        int pos = atomicAdd(&cur[p & 255], 1);
        edge_src[pos] = p >> 8;
    }
}

// =============== MFMA fp16 GEMM, pre-scaled fp16 output (row-major) ===============
// X[M][K] (fp32 or fp16), Wt[BN][K] fp16. XW16[row] = fp16((X@W)[row] * dinv[row]).
template <int BN, int K, typename AT>
__global__ __launch_bounds__(256) void k_gemm_mfma(
    const AT* __restrict__ X, const _Float16* __restrict__ Wt,
    const float* __restrict__ dinv, _Float16* __restrict__ XW16, int M)
{
    constexpr int BM = 64;
    constexpr int BK = 32;
    constexpr int NT = BN / 16;
    constexpr int LDK = BK + 8;   // 40 halfs = 80 B stride, 16B-aligned

    __shared__ __align__(16) _Float16 As[BM][LDK];
    __shared__ __align__(16) _Float16 Bs[BN][LDK];

    const int tid  = threadIdx.x;
    const int wave = tid >> 6;
    const int lane = tid & 63;
    const int m    = lane & 15;
    const int q    = lane >> 4;
    const int rb   = blockIdx.x * BM;

    f32x4 acc[NT];
#pragma unroll
    for (int t = 0; t < NT; t++) acc[t] = (f32x4){0.f, 0.f, 0.f, 0.f};

    for (int kt = 0; kt < K; kt += BK) {
        if (kt) __syncthreads();
        if constexpr (sizeof(AT) == 4) {
#pragma unroll
            for (int i = 0; i < BM * 8 / 256; i++) {
                int ch  = tid + i * 256;
                int row = ch >> 3;
                int c4  = ch & 7;
                int gr  = rb + row;
                float4 v = make_float4(0.f, 0.f, 0.f, 0.f);
                if (gr < M) v = *(const float4*)((const float*)X + (long)gr * K + kt + c4 * 4);
                _Float16* p = &As[row][c4 * 4];
                p[0] = (_Float16)v.x; p[1] = (_Float16)v.y;
                p[2] = (_Float16)v.z; p[3] = (_Float16)v.w;
            }
        } else {
            int row = tid >> 2;
            int c8  = tid & 3;
            int gr  = rb + row;
            uint4 v = make_uint4(0u, 0u, 0u, 0u);
            if (gr < M) v = *(const uint4*)((const _Float16*)X + (long)gr * K + kt + c8 * 8);
            *(uint4*)(&As[row][c8 * 8]) = v;
        }
#pragma unroll
        for (int i = 0; i < BN * 8 / 256; i++) {
            int ch = tid + i * 256;
            int n  = ch >> 3;
            int c4 = ch & 7;
            *(ushort4*)(&Bs[n][c4 * 4]) =
                *(const ushort4*)(Wt + (long)n * K + kt + c4 * 4);
        }
        __syncthreads();

        f16x8 af = *(const f16x8*)(&As[wave * 16 + m][q * 8]);
#pragma unroll
        for (int t = 0; t < NT; t++) {
            f16x8 bf = *(const f16x8*)(&Bs[t * 16 + m][q * 8]);
            acc[t] = __builtin_amdgcn_mfma_f32_16x16x32_f16(af, bf, acc[t], 0, 0, 0);
        }
    }

    int row0 = rb + wave * 16 + q * 4;
#pragma unroll
    for (int r = 0; r < 4; r++) {
        int row = row0 + r;
        if (row < M) {
            float di = dinv[row];
#pragma unroll
            for (int t = 0; t < NT; t++) {
                XW16[(long)row * BN + t * 16 + m] = (_Float16)(acc[t][r] * di);
            }
        }
    }
}

// =============== CSR gather-aggregation (pre-scaled fp16 table, 4x unrolled) ===============
// out[n] = act(bias + dinv[n] * (feat[n] + sum_{e in(n)} feat[src_e]))
template <int F, bool TANH, typename OutT>
__global__ __launch_bounds__(256) void k_agg_csr(const int* __restrict__ row_start,
                                                 const int* __restrict__ edge_src,
                                                 const _Float16* __restrict__ feat,
                                                 const float* __restrict__ bias,
                                                 const float* __restrict__ dinv,
                                                 OutT* __restrict__ out, int M) {
    constexpr int LPN = F / 8;          // lanes per node, 8 halfs (16B) each
    constexpr int NPB = 256 / LPN;
    int n = blockIdx.x * NPB + threadIdx.x / LPN;
    int c = threadIdx.x % LPN;
    if (n >= M) return;
    int beg = row_start[n], end = row_start[n + 1];

    f16x8 self = *(const f16x8*)(feat + (long)n * F + c * 8);
    float acc[8], acc2[8];
#pragma unroll
    for (int k = 0; k < 8; k++) { acc[k] = (float)self[k]; acc2[k] = 0.f; }

    int j = beg;
    for (; j + 3 < end; j += 4) {
        int s0 = edge_src[j],     s1 = edge_src[j + 1];
        int s2 = edge_src[j + 2], s3 = edge_src[j + 3];
        f16x8 v0 = *(const f16x8*)(feat + (long)s0 * F + c * 8);
        f16x8 v1 = *(const f16x8*)(feat + (long)s1 * F + c * 8);
        f16x8 v2 = *(const f16x8*)(feat + (long)s2 * F + c * 8);
        f16x8 v3 = *(const f16x8*)(feat + (long)s3 * F + c * 8);
#pragma unroll
        for (int k = 0; k < 8; k++) {
            acc[k]  += (float)v0[k] + (float)v1[k];
            acc2[k] += (float)v2[k] + (float)v3[k];
        }
    }
    for (; j < end; j++) {
        int s = edge_src[j];
        f16x8 v = *(const f16x8*)(feat + (long)s * F + c * 8);
#pragma unroll
        for (int k = 0; k < 8; k++) acc[k] += (float)v[k];
    }

    float di = dinv[n];
#pragma unroll
    for (int k = 0; k < 8; k++) acc[k] = bias[c * 8 + k] + di * (acc[k] + acc2[k]);
    if (TANH) {
#pragma unroll
        for (int k = 0; k < 8; k++) acc[k] = tanhf(acc[k]);
    }
    if constexpr (sizeof(OutT) == 2) {
        f16x8 o;
#pragma unroll
        for (int k = 0; k < 8; k++) o[k] = (_Float16)acc[k];
        __builtin_nontemporal_store(o, (f16x8*)((_Float16*)out + (long)n * F + c * 8));
    } else {
        f32x4 o0 = {acc[0], acc[1], acc[2], acc[3]};
        f32x4 o1 = {acc[4], acc[5], acc[6], acc[7]};
        float* p = (float*)out + (long)n * F + c * 8;
        __builtin_nontemporal_store(o0, (f32x4*)p);
        __builtin_nontemporal_store(o1, (f32x4*)(p + 4));
    }
}

extern "C" void kernel_launch(void* const* d_in, const int* in_sizes, int n_in,
                              void* d_out, int out_size, void* d_ws, size_t ws_size,
                              hipStream_t stream) {
    const float* x  = (const float*)d_in[0];
    const int*   ei = (const int*)d_in[1];
    const float* W1 = (const float*)d_in[2];
    const float* b1 = (const float*)d_in[3];
    const float* W2 = (const float*)d_in[4];
    const float* b2 = (const float*)d_in[5];
    float* out = (float*)d_out;

    const int M = in_sizes[0] / INDIM;   // 50000
    const int E = in_sizes[1] / 2;       // 800000
    const int* srcp = ei;
    const int* dstp = ei + E;

    const int Mp   = (M + 63) & ~63;
    const int NBIN = (M + 255) >> BINSHIFT;  // 196

    // workspace layout
    float*     dinv       = (float*)d_ws;
    int*       row_start  = (int*)(dinv + Mp);            // [M+1] <= Mp
    int*       bin_start  = row_start + Mp;               // [NBIN+1], padded 258
    int*       bin_cursor = bin_start + 258;
    int*       bin_counts = bin_cursor + MAXBIN;
    _Float16*  W1t        = (_Float16*)(bin_counts + MAXBIN);  // [HID][INDIM]
    _Float16*  W2t        = W1t + HID * INDIM;                 // [OUTD][HID]
    int*       binned     = (int*)(W2t + OUTD * HID);          // [E] packed src<<8|dstlow
    int*       edge_src   = binned + E;                        // [E]
    _Float16*  xw16       = (_Float16*)(edge_src + E);         // [M][HID] pre-scaled
    _Float16*  h16        = xw16 + (long)M * HID;              // [M][HID]
    _Float16*  hw16       = xw16;                              // alias: xw dead after agg1

    const int NWH = (E + 4095) / 4096;   // hist wgs (>=160 needed for weight prep)
    const int NWF = (E + 2047) / 2048;   // binfill wgs

    // ---- build ----
    hipMemsetAsync(bin_counts, 0, MAXBIN * sizeof(int), stream);
    k_hist_setup<<<NWH, 256, 0, stream>>>(dstp, bin_counts, E, W1, W2, W1t, W2t);
    k_bscan<<<1, 256, 0, stream>>>(bin_counts, bin_start, bin_cursor, row_start, NBIN, M, E);
    k_binfill<<<NWF, 256, 0, stream>>>(srcp, dstp, bin_cursor, binned, E);
    k_csr<<<NBIN, 256, 0, stream>>>(binned, bin_start, row_start, dinv, edge_src, M);

    // ---- layer 1: xw16 = fp16((x@W1)*dinv) ; h16 = tanh(b1 + dinv*(self + edges)) ----
    k_gemm_mfma<HID, INDIM, float><<<(M + 63) / 64, 256, 0, stream>>>(x, W1t, dinv, xw16, M);
    k_agg_csr<HID, true, _Float16><<<(M + 15) / 16, 256, 0, stream>>>(row_start, edge_src, xw16, b1, dinv, h16, M);

    // ---- layer 2: hw16 = fp16((h@W2)*dinv) ; out = b2 + dinv*(self + edges) ----
    k_gemm_mfma<OUTD, HID, _Float16><<<(M + 63) / 64, 256, 0, stream>>>(h16, W2t, dinv, hw16, M);
    k_agg_csr<OUTD, false, float><<<(M + 31) / 32, 256, 0, stream>>>(row_start, edge_src, hw16, b2, dinv, out, M);
}